// Round 1
// 858.341 us; speedup vs baseline: 1.0786x; 1.0786x over previous
//
#include <hip/hip_runtime.h>
#include <cstdint>
#include <cstddef>

#define B_ROWS 16384
#define DIM    768
#define HID    16384
#define BM     256            // tile M = N = 256
#define BK     64
#define KT_N   (DIM / BK)     // 12 K-tiles
#define NCB    (HID / BM)     // 64 column blocks per row

typedef __bf16 bf16x8 __attribute__((ext_vector_type(8)));
typedef float  f32x4  __attribute__((ext_vector_type(4)));
typedef unsigned int   u32;
typedef unsigned short u16;

// ---------- helpers ----------
__device__ __forceinline__ u32 umaxu(u32 a, u32 b) { return a > b ? a : b; }
__device__ __forceinline__ u32 uminu(u32 a, u32 b) { return a < b ? a : b; }

// fp32 -> bf16 (RNE)
__device__ __forceinline__ u16 f2bf(float f) {
    u32 u = __float_as_uint(f);
    return (u16)((u + 0x7FFFu + ((u >> 16) & 1u)) >> 16);
}

// screening key: monotone-mapped bf16(value) in high 16 bits, latent idx in low 16.
__device__ __forceinline__ u32 pk(float v, int gidx) {
    u32 b = __float_as_uint(v);
    u32 t = b >> 16;
    t ^= (b & 0x80000000u) ? 0xFFFFu : 0x8000u;
    return (t << 16) | (u32)gidx;
}

// async global->LDS, 16B/lane; LDS dest = wave-uniform base + lane*16
__device__ __forceinline__ void gll16(const void* g, void* l) {
    __builtin_amdgcn_global_load_lds(
        (const __attribute__((address_space(1))) unsigned int*)g,
        (__attribute__((address_space(3))) unsigned int*)l, 16, 0, 0);
}

// merge two sorted triples -> top-3 of 6 (network verified in prior kernel)
__device__ __forceinline__ void merge3(u32& z0, u32& z1, u32& z2,
                                       u32 A0, u32 A1, u32 A2,
                                       u32 B0, u32 B1, u32 B2) {
    const u32 P = uminu(A0, B0), Q = umaxu(A1, B1);
    const u32 R = uminu(A1, B1), S = umaxu(A2, B2);
    z0 = umaxu(A0, B0);
    z1 = umaxu(P, Q);
    z2 = umaxu(umaxu(uminu(P, Q), R), S);
}

// exact-stage top-3 (tie-break: lower index wins, matching jax.lax.top_k)
__device__ __forceinline__ bool better(float v1, int i1, float v2, int i2) {
    return (v1 > v2) || (v1 == v2 && i1 < i2);
}
__device__ __forceinline__ void ins3(float v, int i,
                                     float& v0, int& i0, float& v1, int& i1,
                                     float& v2, int& i2) {
    if (better(v, i, v2, i2)) {
        v2 = v; i2 = i;
        if (better(v2, i2, v1, i1)) { float tv = v1; int ti = i1; v1 = v2; i1 = i2; v2 = tv; i2 = ti; }
        if (better(v1, i1, v0, i0)) { float tv = v0; int ti = i0; v0 = v1; i0 = i1; v1 = tv; i1 = ti; }
    }
}

// ---------- cast X and W_enc to bf16 ----------
__global__ __launch_bounds__(256) void cast_bf16(const float* __restrict__ X,
                                                 const float* __restrict__ W,
                                                 u16* __restrict__ Xb, u16* __restrict__ Wb) {
    const int n4 = (B_ROWS * DIM) / 4;
    for (int i = blockIdx.x * blockDim.x + threadIdx.x; i < n4; i += gridDim.x * blockDim.x) {
        float4 x = ((const float4*)X)[i];
        float4 w = ((const float4*)W)[i];
        ushort4 xo, wo;
        xo.x = f2bf(x.x); xo.y = f2bf(x.y); xo.z = f2bf(x.z); xo.w = f2bf(x.w);
        wo.x = f2bf(w.x); wo.y = f2bf(w.y); wo.z = f2bf(w.z); wo.w = f2bf(w.w);
        ((ushort4*)Xb)[i] = xo;
        ((ushort4*)Wb)[i] = wo;
    }
}

// ---------- 256x256 8-phase bf16 MFMA GEMM + fused per-(row,256-col-block) top-3 screening ----------
// 8 waves 2(M)x4(N); wave tile 128x64; BK=64; LDS 128 KiB double-buffered.
// Per K-tile: 4 phases {ds_read frags | stage one 16KB half-slab of tile t+1 |
//   s_barrier | 16 MFMA (setprio) | counted vmcnt | s_barrier}.
// LDS swizzle: 16B-chunk slot = chunk ^ (row&7); row stride = 128 B = 32 banks,
// so frag ds_read_b128 lands 2-way (free). Source is pre-swizzled (rule #21).
__global__ __launch_bounds__(512, 2) void gemm_screen(const u16* __restrict__ Xb,
                                                      const u16* __restrict__ Wb,
                                                      const float* __restrict__ benc,
                                                      u32* __restrict__ pvpi) {
    __shared__ __align__(16) u16 As[2 * BM * BK];   // 64 KiB
    __shared__ __align__(16) u16 Bs[2 * BM * BK];   // 64 KiB

    // T1: bijective XCD swizzle (4096 % 8 == 0) then 16x16 supertiles
    const int bid = blockIdx.x;
    const int wg = ((bid & 7) << 9) | (bid >> 3);
    const int st = wg >> 8, loc = wg & 255;
    const int rb = ((st >> 2) << 4) | (loc >> 4);
    const int cb = ((st & 3) << 4) | (loc & 15);
    const int rowBase = rb * BM, colBase = cb * BM;

    const int tid = threadIdx.x;
    const int wid = tid >> 6, lane = tid & 63;
    const int wm = wid >> 2, wn = wid & 3;       // wave -> (row half, col quarter)
    const int j = lane & 15, g = lane >> 4;
    const int js = j & 7;

    // staging source mapping: thread stages LDS 16B-slot (q*512+tid);
    // row r = q*64 + (tid>>3), slot s = tid&7, logical chunk c = s ^ (r&7)
    const int sr = tid >> 3, ss = tid & 7;
    const int sc = ss ^ (sr & 7);
    const u32 aoff = (u32)(rowBase + sr) * DIM + (u32)sc * 8;
    const u32 boff = (u32)(colBase + sr) * DIM + (u32)sc * 8;
    const int lbw = wid * 512;                   // wave-uniform LDS u16 base within a round

#define STAGE_A(H, KTL, D1) do { \
    gll16(Xb + aoff + (H) * 98304u + (u32)(KTL) * 64u,           As + (D1) * 16384 + (H) * 8192 + lbw); \
    gll16(Xb + aoff + (H) * 98304u + 49152u + (u32)(KTL) * 64u,  As + (D1) * 16384 + (H) * 8192 + 4096 + lbw); \
} while (0)
#define STAGE_B(H, KTL, D1) do { \
    gll16(Wb + boff + (H) * 98304u + (u32)(KTL) * 64u,           Bs + (D1) * 16384 + (H) * 8192 + lbw); \
    gll16(Wb + boff + (H) * 98304u + 49152u + (u32)(KTL) * 64u,  Bs + (D1) * 16384 + (H) * 8192 + 4096 + lbw); \
} while (0)

    const bf16x8* As8 = (const bf16x8*)As;
    const bf16x8* Bs8 = (const bf16x8*)Bs;

    // frag reads (16B units): idx = row*8 + ((kk*4+g) ^ (row&7)); row&7 == j&7 here
#define READ_A(MH, D) do { \
    _Pragma("unroll") for (int mtl = 0; mtl < 4; ++mtl) { \
        const int m8_ = (D) * 2048 + (wm * 128 + ((MH) * 4 + mtl) * 16 + j) * 8; \
        aF[mtl][0] = As8[m8_ + ((0 + g) ^ js)]; \
        aF[mtl][1] = As8[m8_ + ((4 + g) ^ js)]; \
    } } while (0)
#define READ_B(DST, NH, D) do { \
    _Pragma("unroll") for (int ntl = 0; ntl < 2; ++ntl) { \
        const int n8_ = (D) * 2048 + (wn * 64 + ((NH) * 2 + ntl) * 16 + j) * 8; \
        DST[ntl][0] = Bs8[n8_ + ((0 + g) ^ js)]; \
        DST[ntl][1] = Bs8[n8_ + ((4 + g) ^ js)]; \
    } } while (0)

#define MFMA_Q(MH, NH, BF) do { \
    __builtin_amdgcn_s_setprio(1); \
    _Pragma("unroll") for (int kk2 = 0; kk2 < 2; ++kk2) \
    _Pragma("unroll") for (int mtl = 0; mtl < 4; ++mtl) \
    _Pragma("unroll") for (int ntl = 0; ntl < 2; ++ntl) \
        acc[(MH) * 4 + mtl][(NH) * 2 + ntl] = __builtin_amdgcn_mfma_f32_16x16x32_bf16( \
            aF[mtl][kk2], BF[ntl][kk2], acc[(MH) * 4 + mtl][(NH) * 2 + ntl], 0, 0, 0); \
    __builtin_amdgcn_s_setprio(0); \
} while (0)

    f32x4 acc[8][4];
#pragma unroll
    for (int mt = 0; mt < 8; ++mt)
#pragma unroll
        for (int nt = 0; nt < 4; ++nt) acc[mt][nt] = (f32x4){0.f, 0.f, 0.f, 0.f};

    // prologue: tile 0 -> dbuf 0, unit order = first-read order {A-lo, B-lo, B-hi, A-hi}
    STAGE_A(0, 0, 0); STAGE_B(0, 0, 0); STAGE_B(1, 0, 0); STAGE_A(1, 0, 0);
    asm volatile("s_waitcnt vmcnt(4)" ::: "memory");   // A-lo,B-lo landed; B-hi,A-hi in flight
    __builtin_amdgcn_s_barrier();

    bf16x8 aF[4][2], bLo[2][2], bHi[2][2];

#pragma unroll 1
    for (int t = 0; t < KT_N; ++t) {
        const int d = t & 1, d1 = d ^ 1;
        const bool stg = (t + 1 < KT_N);
        const int kt = t + 1;

        // ---- phase 0: Q(lo,lo); reads a-lo + b-lo; stages A-lo(t+1)
        READ_A(0, d);
        READ_B(bLo, 0, d);
        if (stg) STAGE_A(0, kt, d1);
        __builtin_amdgcn_s_barrier();
        MFMA_Q(0, 0, bLo);
        if (stg) asm volatile("s_waitcnt vmcnt(4)" ::: "memory");  // lands B-hi(t)
        else     asm volatile("s_waitcnt vmcnt(2)" ::: "memory");
        __builtin_amdgcn_s_barrier();

        // ---- phase 1: Q(lo,hi); reads b-hi; stages B-lo(t+1)
        READ_B(bHi, 1, d);
        if (stg) STAGE_B(0, kt, d1);
        __builtin_amdgcn_s_barrier();
        MFMA_Q(0, 1, bHi);
        if (stg) asm volatile("s_waitcnt vmcnt(4)" ::: "memory");  // lands A-hi(t)
        else     asm volatile("s_waitcnt vmcnt(0)" ::: "memory");
        __builtin_amdgcn_s_barrier();

        // ---- phase 2: Q(hi,hi); reads a-hi; stages B-hi(t+1); no vmcnt needed after
        READ_A(1, d);
        if (stg) STAGE_B(1, kt, d1);
        __builtin_amdgcn_s_barrier();
        MFMA_Q(1, 1, bHi);
        __builtin_amdgcn_s_barrier();

        // ---- phase 3: Q(hi,lo); pure-reg (bLo kept); stages A-hi(t+1)
        if (stg) STAGE_A(1, kt, d1);
        __builtin_amdgcn_s_barrier();
        MFMA_Q(1, 0, bLo);
        if (stg) asm volatile("s_waitcnt vmcnt(4)" ::: "memory");  // lands A-lo,B-lo(t+1)
        __builtin_amdgcn_s_barrier();
    }

    // ================= fused screening epilogue =================
    __syncthreads();                 // full drain; LDS reusable
    u32* sm = (u32*)As;              // [256 rows][4 wn][3] = 12 KiB overlay

    float bias[4]; int gcol[4];
#pragma unroll
    for (int nt = 0; nt < 4; ++nt) {
        gcol[nt] = colBase + wn * 64 + nt * 16 + j;
        bias[nt] = benc[gcol[nt]];
    }

    // C/D layout: col = lane&15 (+nt*16), row = (lane>>4)*4 + reg (+mt*16)  [m89]
#pragma unroll
    for (int mt = 0; mt < 8; ++mt) {
#pragma unroll
        for (int reg = 0; reg < 4; ++reg) {
            const u32 k0 = pk(acc[mt][0][reg] + bias[0], gcol[0]);
            const u32 k1 = pk(acc[mt][1][reg] + bias[1], gcol[1]);
            const u32 k2 = pk(acc[mt][2][reg] + bias[2], gcol[2]);
            const u32 k3 = pk(acc[mt][3][reg] + bias[3], gcol[3]);
            // sorted top-3 of 4
            u32 a0 = umaxu(k0, k1), a1 = uminu(k0, k1);
            u32 b0 = umaxu(k2, k3), b1 = uminu(k2, k3);
            u32 x0 = umaxu(a0, b0);
            u32 p = uminu(a0, b0), q = umaxu(a1, b1), r2 = uminu(a1, b1);
            u32 x1 = umaxu(p, q);
            u32 x2 = umaxu(uminu(p, q), r2);
            // butterfly merge across the 16 lanes of this row
#pragma unroll
            for (int mk = 1; mk < 16; mk <<= 1) {
                const u32 y0 = (u32)__shfl_xor((int)x0, mk, 64);
                const u32 y1 = (u32)__shfl_xor((int)x1, mk, 64);
                const u32 y2 = (u32)__shfl_xor((int)x2, mk, 64);
                u32 z0, z1, z2;
                merge3(z0, z1, z2, x0, x1, x2, y0, y1, y2);
                x0 = z0; x1 = z1; x2 = z2;
            }
            if ((lane & 15) == 0) {
                const int row = wm * 128 + mt * 16 + g * 4 + reg;
                sm[row * 12 + wn * 3 + 0] = x0;
                sm[row * 12 + wn * 3 + 1] = x1;
                sm[row * 12 + wn * 3 + 2] = x2;
            }
        }
    }
    __syncthreads();
    // merge the 4 wave-quarters per row, write pvpi[row][cb][3]
    if (tid < 256) {
        const int row = tid;
        const u32* s = sm + row * 12;
        u32 m0, m1, m2, n0, n1, n2, z0, z1, z2;
        merge3(m0, m1, m2, s[0], s[1], s[2], s[3], s[4], s[5]);
        merge3(n0, n1, n2, s[6], s[7], s[8], s[9], s[10], s[11]);
        merge3(z0, z1, z2, m0, m1, m2, n0, n1, n2);
        const size_t base = ((size_t)(rowBase + row) * NCB + cb) * 3;
        pvpi[base + 0] = z0; pvpi[base + 1] = z1; pvpi[base + 2] = z2;
    }
#undef STAGE_A
#undef STAGE_B
#undef READ_A
#undef READ_B
#undef MFMA_Q
}

// ---------- reduce 192 screening keys -> top-16 candidates -> exact fp32 recheck ----------
__global__ __launch_bounds__(256) void reduce_recheck(
        const u32* __restrict__ pvpi, const float* __restrict__ X,
        const float* __restrict__ Wenc, const float* __restrict__ benc,
        float* __restrict__ fv, int* __restrict__ fi, int* __restrict__ mask) {
    const int wid = threadIdx.x >> 6, lane = threadIdx.x & 63;
    const int row = blockIdx.x * 4 + wid;

    const u32* p = pvpi + (size_t)row * (NCB * 3);
    u32 k[3];
#pragma unroll
    for (int t = 0; t < 3; t++) k[t] = p[t * 64 + lane];

    // extract top-16 keys (keys unique: latent idx in low bits)
    u32 cand[16];
#pragma unroll
    for (int it = 0; it < 16; ++it) {
        u32 m = umaxu(umaxu(k[0], k[1]), k[2]);
#pragma unroll
        for (int mk = 1; mk < 64; mk <<= 1) m = umaxu(m, (u32)__shfl_xor((int)m, mk, 64));
        cand[it] = m;
#pragma unroll
        for (int t = 0; t < 3; t++) if (k[t] == m) k[t] = 0;
    }

    // exact fp32 recheck: lane covers dims [lane*12, lane*12+12)
    const float4* xp = (const float4*)(X + (size_t)row * DIM) + lane * 3;
    const float4 x0 = xp[0], x1 = xp[1], x2 = xp[2];

    float v0 = -INFINITY, v1 = -INFINITY, v2 = -INFINITY;
    int   i0 = 0x7fffffff, i1 = 0x7fffffff, i2 = 0x7fffffff;
#pragma unroll
    for (int it = 0; it < 16; ++it) {
        const int ci = (int)(cand[it] & 0xFFFFu);
        const float4* wq = (const float4*)(Wenc + (size_t)ci * DIM) + lane * 3;
        const float4 w0 = wq[0], w1 = wq[1], w2 = wq[2];
        float s = x0.x * w0.x;
        s = fmaf(x0.y, w0.y, s); s = fmaf(x0.z, w0.z, s); s = fmaf(x0.w, w0.w, s);
        s = fmaf(x1.x, w1.x, s); s = fmaf(x1.y, w1.y, s); s = fmaf(x1.z, w1.z, s);
        s = fmaf(x1.w, w1.w, s); s = fmaf(x2.x, w2.x, s); s = fmaf(x2.y, w2.y, s);
        s = fmaf(x2.z, w2.z, s); s = fmaf(x2.w, w2.w, s);
#pragma unroll
        for (int mk = 1; mk < 64; mk <<= 1) s += __shfl_xor(s, mk, 64);
        const float val = s + benc[ci];
        ins3(val, ci, v0, i0, v1, i1, v2, i2);
    }
    if (lane == 0) {
        fv[row * 3 + 0] = v0; fv[row * 3 + 1] = v1; fv[row * 3 + 2] = v2;
        fi[row * 3 + 0] = i0; fi[row * 3 + 1] = i1; fi[row * 3 + 2] = i2;
        mask[i0] = 1; mask[i1] = 1; mask[i2] = 1;
    }
}

// ---------- count live latents ----------
__global__ __launch_bounds__(256) void count_live(const int* __restrict__ mask,
                                                  float* __restrict__ outScalar) {
    __shared__ int sd[256];
    const int tid = threadIdx.x;
    int s = 0;
    for (int i = tid; i < HID; i += 256) s += mask[i];
    sd[tid] = s;
    __syncthreads();
    for (int st = 128; st > 0; st >>= 1) {
        if (tid < st) sd[tid] += sd[tid + st];
        __syncthreads();
    }
    if (tid == 0) outScalar[0] = (float)sd[0];
}

// ---------- transpose W_dec [DIM][HID] -> Wt [HID][DIM] ----------
__global__ __launch_bounds__(256) void transpose_wdec(const float* __restrict__ W,
                                                      float* __restrict__ Wt) {
    __shared__ float t[32][33];
    const int bx = blockIdx.x;
    const int by = blockIdx.y;
    const int x = threadIdx.x & 31;
    const int y = threadIdx.x >> 5;
#pragma unroll
    for (int i = 0; i < 4; i++) {
        const int d = by * 32 + y + i * 8;
        t[y + i * 8][x] = W[(size_t)d * HID + bx * 32 + x];
    }
    __syncthreads();
#pragma unroll
    for (int i = 0; i < 4; i++) {
        const int h = bx * 32 + y + i * 8;
        Wt[(size_t)h * DIM + by * 32 + x] = t[x][y + i * 8];
    }
}

// ---------- sparse decode ----------
__global__ __launch_bounds__(192) void decode_rows(
        const float* __restrict__ fv, const int* __restrict__ fi,
        const float* __restrict__ Wt, const float* __restrict__ bdec,
        float* __restrict__ out) {
    const int row = blockIdx.x;
    const int tid = threadIdx.x;
    const float v0 = fv[row * 3 + 0], v1 = fv[row * 3 + 1], v2 = fv[row * 3 + 2];
    const int   i0 = fi[row * 3 + 0], i1 = fi[row * 3 + 1], i2 = fi[row * 3 + 2];
    const int jj = tid * 4;
    const float4 b  = *(const float4*)(bdec + jj);
    const float4 w0 = *(const float4*)(Wt + (size_t)i0 * DIM + jj);
    const float4 w1 = *(const float4*)(Wt + (size_t)i1 * DIM + jj);
    const float4 w2 = *(const float4*)(Wt + (size_t)i2 * DIM + jj);
    float4 o;
    o.x = b.x + v0 * w0.x + v1 * w1.x + v2 * w2.x;
    o.y = b.y + v0 * w0.y + v1 * w1.y + v2 * w2.y;
    o.z = b.z + v0 * w0.z + v1 * w1.z + v2 * w2.z;
    o.w = b.w + v0 * w0.w + v1 * w1.w + v2 * w2.w;
    *(float4*)(out + (size_t)row * DIM + jj) = o;
}

extern "C" void kernel_launch(void* const* d_in, const int* in_sizes, int n_in,
                              void* d_out, int out_size, void* d_ws, size_t ws_size,
                              hipStream_t stream) {
    const float* X    = (const float*)d_in[0];   // [B, DIM]
    const float* Wenc = (const float*)d_in[1];   // [HID, DIM]
    const float* benc = (const float*)d_in[2];   // [HID]
    const float* Wdec = (const float*)d_in[3];   // [DIM, HID]
    const float* bdec = (const float*)d_in[4];   // [DIM]
    float* out = (float*)d_out;                  // [B*DIM] recon + [1] num_live

    // workspace layout (bytes):
    //   [0, 25165824)            Xb bf16        -- dead after gemm
    //   [25165824, 50331648)     Wb bf16        -- dead after gemm
    //   [0, 50331648)            Wt fp32        -- REUSES Xb+Wb after gemm
    //   [50331648, 62914560)     pvpi packed keys [B][64][3]
    //   [62914560, +196608)      fv
    //   [63111168, +196608)      fi
    //   [63307776, +65536)       mask
    char* ws = (char*)d_ws;
    u16*   Xb   = (u16*)ws;
    u16*   Wb   = (u16*)(ws + 25165824);
    float* Wt   = (float*)ws;
    u32*   pvpi = (u32*)(ws + 50331648);
    float* fv   = (float*)(ws + 62914560);
    int*   fi   = (int*)(ws + 63111168);
    int*   mask = (int*)(ws + 63307776);

    hipMemsetAsync(mask, 0, HID * sizeof(int), stream);

    cast_bf16<<<3072, 256, 0, stream>>>(X, Wenc, Xb, Wb);
    gemm_screen<<<4096, 512, 0, stream>>>(Xb, Wb, benc, pvpi);
    reduce_recheck<<<B_ROWS / 4, 256, 0, stream>>>(pvpi, X, Wenc, benc, fv, fi, mask);
    count_live<<<1, 256, 0, stream>>>(mask, out + (size_t)B_ROWS * DIM);
    // transpose overwrites Xb/Wb (dead after gemm)
    transpose_wdec<<<dim3(HID / 32, DIM / 32), 256, 0, stream>>>(Wdec, Wt);
    decode_rows<<<B_ROWS, 192, 0, stream>>>(fv, fi, Wt, bdec, out);
}